// Round 15
// baseline (98.280 us; speedup 1.0000x reference)
//
#include <hip/hip_runtime.h>
#include <hip/hip_bf16.h>

#define D_MODEL 1024
#define NQKV 3072

typedef __attribute__((ext_vector_type(8))) short bf16x8;
typedef __attribute__((ext_vector_type(4))) float f32x4;
typedef __attribute__((ext_vector_type(16))) float f32x16;
typedef __attribute__((ext_vector_type(8))) unsigned short u16x8;

static __device__ __forceinline__ unsigned short f2bf(float f){
  unsigned int x = __float_as_uint(f);
  x += 0x7fff + ((x >> 16) & 1);   // RNE
  return (unsigned short)(x >> 16);
}
static __device__ __forceinline__ float bf2f(unsigned short u){
  return __uint_as_float(((unsigned int)u) << 16);
}

// ---------------- LayerNorm -> bf16 ----------------
__global__ __launch_bounds__(256) void ln_kernel(const float* __restrict__ inp,
    const float* __restrict__ gamma, const float* __restrict__ beta,
    unsigned short* __restrict__ X){
  const int row = blockIdx.x;
  const int t = threadIdx.x;
  const float4* ip = (const float4*)(inp + (size_t)row * D_MODEL);
  float4 v = ip[t];
  float s1 = v.x + v.y + v.z + v.w;
  float s2 = v.x*v.x + v.y*v.y + v.z*v.z + v.w*v.w;
#pragma unroll
  for (int off = 32; off >= 1; off >>= 1){
    s1 += __shfl_down(s1, off);
    s2 += __shfl_down(s2, off);
  }
  __shared__ float red[8];
  const int wave = t >> 6, lane = t & 63;
  if (lane == 0){ red[wave] = s1; red[4 + wave] = s2; }
  __syncthreads();
  s1 = red[0] + red[1] + red[2] + red[3];
  s2 = red[4] + red[5] + red[6] + red[7];
  const float mu   = s1 * (1.0f / D_MODEL);
  const float var  = s2 * (1.0f / D_MODEL) - mu * mu;
  const float rstd = rsqrtf(var + 1e-5f);
  float4 g = ((const float4*)gamma)[t];
  float4 b = ((const float4*)beta)[t];
  ushort4 o;
  o.x = f2bf((v.x - mu) * rstd * g.x + b.x);
  o.y = f2bf((v.y - mu) * rstd * g.y + b.y);
  o.z = f2bf((v.z - mu) * rstd * g.z + b.z);
  o.w = f2bf((v.w - mu) * rstd * g.w + b.w);
  ((ushort4*)(X + (size_t)row * D_MODEL))[t] = o;
}

// --- W transpose + fp32->bf16 (Wt[n][k] = W[k][n]) + fused bias concat ---
__global__ __launch_bounds__(256) void wtrans_kernel(const float* __restrict__ Wq,
    const float* __restrict__ Wk, const float* __restrict__ Wv,
    const float* __restrict__ bq, const float* __restrict__ bk,
    const float* __restrict__ bv, unsigned short* __restrict__ Wt,
    float* __restrict__ bc){
  __shared__ float tile[32][33];
  const int z = blockIdx.z;
  const float* W = (z == 0) ? Wq : ((z == 1) ? Wk : Wv);
  const int k0 = blockIdx.x * 32, n0 = blockIdx.y * 32;
  const int r = threadIdx.x >> 5, c = threadIdx.x & 31;
  if (blockIdx.x == 0 && r == 0){
    const float* bsrc = (z == 0) ? bq : ((z == 1) ? bk : bv);
    bc[z * 1024 + n0 + c] = bsrc[n0 + c];
  }
#pragma unroll
  for (int i = 0; i < 4; i++)
    tile[r + i*8][c] = W[(size_t)(k0 + r + i*8) * D_MODEL + n0 + c];
  __syncthreads();
  unsigned short* dst = Wt + (size_t)(z * D_MODEL + n0) * D_MODEL + k0;
#pragma unroll
  for (int i = 0; i < 4; i++){
    int rr = r + i*8;
    dst[(size_t)rr * D_MODEL + c] = f2bf(tile[c][rr]);
  }
}

// ====== 128x256 GEMM, BK=64, 3-buffer, 2D XCD chunks, 2-phase role-split ======
// QKV[8192][3072] = Xln @ Wt^T + b.  A row-major, Bt [N][K] K-major.
// R15 (vs R14, single variable): each K-tile's BODY split into TWO phases
// (kh0 / kh1), each phase = { 8 ds_read_b128 ; 3 staging GLL ; s_barrier ;
// lgkmcnt(0) ; setprio(1) 16 MFMA setprio(0) ; s_barrier }.  Mechanism (T5
// catalog): setprio pays only when a phase-split creates wave role diversity
// (m218b/m224 +21-39%; null on single-phase lockstep, m190). Prior phase-split
// attempts failed with reads-AFTER-barrier (R3) + HBM-latency staging; both
// fixed (reads-before-barrier per R10; L2-hot staging per R14's 2D XCD chunks).
// vmcnt(6) once per K-tile at ph1 (same guarantee as R14: tile t+1 landed,
// t+2's 6 loads in flight). 4 barriers/K-tile = m201's rate.
// LDS XOR-swizzle byte ^= ((row&7)<<4); global source pre-swizzled.

#define GLL(src, dst) __builtin_amdgcn_global_load_lds( \
    (const __attribute__((address_space(1))) void*)(src), \
    (__attribute__((address_space(3))) void*)(dst), 16, 0, 0)

// tile staging = 6 GLL/thread: A 2 + B 4.  Split 3 + 3 across the two phases.
#define STAGE_P0(tsrc, bi) do { \
  const char* _sa = Ag + (size_t)r0*2048 + (size_t)(tsrc)*128 + co; \
  char* _da = ldsS + (size_t)(bi)*49152 + tid*16; \
  GLL(_sa, _da); GLL(_sa + 131072, _da + 8192); \
  const char* _sb = Bg + (size_t)r0*2048 + (size_t)(tsrc)*128 + co; \
  char* _db = ldsS + (size_t)(bi)*49152 + 16384 + tid*16; \
  GLL(_sb, _db); \
} while(0)

#define STAGE_P1(tsrc, bi) do { \
  const char* _sb = Bg + (size_t)r0*2048 + (size_t)(tsrc)*128 + co; \
  char* _db = ldsS + (size_t)(bi)*49152 + 16384 + tid*16; \
  GLL(_sb + 131072, _db + 8192); \
  GLL(_sb + 262144, _db + 16384); GLL(_sb + 393216, _db + 24576); \
} while(0)

// one phase's compute: 4 A-frags + 4 B-frags at column cb, 16 MFMA
#define PHASE_READS(bi, cb) do { \
  const char* Ab = ldsS + (size_t)(bi)*49152 + (wr*64 + lr)*128; \
  const char* Bb = ldsS + (size_t)(bi)*49152 + 16384 + (wc*64 + lr)*128; \
  _Pragma("unroll") \
  for (int m = 0; m < 4; m++) Ar[m] = *(const bf16x8*)(Ab + m*2048 + (cb)); \
  _Pragma("unroll") \
  for (int n = 0; n < 4; n++) Br[n] = *(const bf16x8*)(Bb + n*2048 + (cb)); \
} while(0)

#define PHASE_MFMA do { \
  __builtin_amdgcn_s_setprio(1); \
  _Pragma("unroll") \
  for (int m = 0; m < 4; m++) \
    _Pragma("unroll") \
    for (int n = 0; n < 4; n++) \
      acc[m][n] = __builtin_amdgcn_mfma_f32_16x16x32_bf16(Ar[m], Br[n], acc[m][n], 0, 0, 0); \
  __builtin_amdgcn_s_setprio(0); \
} while(0)

#define BARRIER __builtin_amdgcn_s_barrier()
#define SCHEDB  __builtin_amdgcn_sched_barrier(0)
#define VMCNT6  asm volatile("s_waitcnt vmcnt(6)" ::: "memory")
#define VMCNT0  asm volatile("s_waitcnt vmcnt(0)" ::: "memory")
#define LGKM0   asm volatile("s_waitcnt lgkmcnt(0)" ::: "memory")

__global__ __launch_bounds__(512, 2) void gemm128x256_kernel(const unsigned short* __restrict__ A,
    const unsigned short* __restrict__ Bt, const float* __restrict__ bias,
    unsigned short* __restrict__ C){
  __shared__ __align__(16) char ldsS[3 * 49152];   // 144 KiB
  const int tid = threadIdx.x;
  const int wave = tid >> 6, lane = tid & 63;
  const int wr = wave >> 2, wc = wave & 3;         // 2M x 4N wave grid
  const int lr = lane & 15;
  const int colb0 = ((lane >> 4) * 16) ^ ((lane & 7) << 4);
  const int colb1 = (64 + (lane >> 4) * 16) ^ ((lane & 7) << 4);

  // 2D XCD-chunked mapping (R14): XCD x owns M-tiles [x*8, x*8+8) x 12 N-tiles.
  const int b = blockIdx.x;
  const int xcd = b & 7;
  const int i = b >> 3;                            // 0..95 within XCD
  const int mi = i & 7, ni = i >> 3;               // 8 M x 12 N, M fastest
  const int m0 = (xcd * 8 + mi) * 128;
  const int n0 = ni * 256;

  const int r0 = tid >> 3;
  const size_t co = (size_t)(((tid & 7) * 16) ^ ((r0 & 7) << 4));
  const char* Ag = (const char*)(A + (size_t)m0 * 1024);
  const char* Bg = (const char*)(Bt + (size_t)n0 * 1024);

  f32x4 acc[4][4] = {};
  bf16x8 Ar[4], Br[4];

  // prologue: stage tiles 0,1 into bufs 0,1; require tile 0 landed (tile 1 may fly)
  STAGE_P0(0, 0); STAGE_P1(0, 0);
  STAGE_P0(1, 1); STAGE_P1(1, 1);
  VMCNT6; BARRIER; SCHEDB;

  for (int t = 0; t < 16; ++t){
    const int buf = t % 3;
    const int nbuf = (t + 2) % 3;
    // ---- phase 0 (kh0) ----
    PHASE_READS(buf, colb0);
    if (t <= 13) STAGE_P0(t + 2, nbuf);
    BARRIER;
    LGKM0; SCHEDB;
    PHASE_MFMA;
    BARRIER; SCHEDB;
    // ---- phase 1 (kh1) ----
    PHASE_READS(buf, colb1);
    if (t <= 13) STAGE_P1(t + 2, nbuf);
    if (t <= 13)      { SCHEDB; VMCNT6; }   // tile t+1 landed; t+2's 6 in flight
    else if (t == 14) { SCHEDB; VMCNT0; }   // tile 15 fully landed
    BARRIER;
    LGKM0; SCHEDB;
    PHASE_MFMA;
    if (t < 15) { BARRIER; SCHEDB; }        // t==15: epilogue is LDS-free
  }

  // epilogue: bias + bf16 store (per-wave 64x64)
  const int gm = m0 + wr*64;
  const int gn = n0 + wc*64;
  const int rr0 = (lane >> 4) * 4;
#pragma unroll
  for (int nf = 0; nf < 4; nf++){
    const int gcol = gn + nf*16 + lr;
    const float bb = bias[gcol];
#pragma unroll
    for (int mf = 0; mf < 4; mf++){
      const int grow = gm + mf*16 + rr0;
#pragma unroll
      for (int r = 0; r < 4; r++)
        C[(size_t)(grow + r) * NQKV + gcol] = f2bf(acc[mf][nf][r] + bb);
    }
  }
}

// ---------------- per-token attention + residual (MFMA, swapped-QK^T) ----------------
__global__ __launch_bounds__(256) void attn_kernel(const unsigned short* __restrict__ qkv,
    const float* __restrict__ inp, float* __restrict__ out){
  __shared__ unsigned short P[4][64 * 64];
  const int wave = threadIdx.x >> 6, lane = threadIdx.x & 63;
  const int token = blockIdx.x * 4 + wave;
  const unsigned short* row = qkv + (size_t)token * NQKV;
  const int l31 = lane & 31, hi = lane >> 5;
  const int l15 = lane & 15, qg = lane >> 4;
  char* pbase = (char*)&P[wave][0];

  bf16x8 kf[2], qf[2];
#pragma unroll
  for (int mt = 0; mt < 2; mt++)
    kf[mt] = *(const bf16x8*)(row + 1024 + (mt*32 + l31)*16 + hi*8);
#pragma unroll
  for (int nt = 0; nt < 2; nt++)
    qf[nt] = *(const bf16x8*)(row + (nt*32 + l31)*16 + hi*8);

  bf16x8 vf[2];
#pragma unroll
  for (int kc = 0; kc < 2; kc++)
#pragma unroll
    for (int e = 0; e < 8; e++)
      vf[kc][e] = (short)row[2048 + (kc*32 + qg*8 + e)*16 + l15];

  f32x16 s[2][2] = {};
#pragma unroll
  for (int mt = 0; mt < 2; mt++)
#pragma unroll
    for (int nt = 0; nt < 2; nt++)
      s[mt][nt] = __builtin_amdgcn_mfma_f32_32x32x16_bf16(kf[mt], qf[nt], s[mt][nt], 0, 0, 0);

#pragma unroll
  for (int ti = 0; ti < 2; ti++){
    float m = s[0][ti][0];
#pragma unroll
    for (int mt = 0; mt < 2; mt++)
#pragma unroll
      for (int r = 0; r < 16; r++) m = fmaxf(m, s[mt][ti][r]);
    m = fmaxf(m, __shfl_xor(m, 32));
    float sum = 0.0f;
#pragma unroll
    for (int mt = 0; mt < 2; mt++)
#pragma unroll
      for (int r = 0; r < 16; r++){
        float p = exp2f((s[mt][ti][r] - m) * 0.1803368801f); // 0.125 * log2(e)
        s[mt][ti][r] = p;
        sum += p;
      }
    sum += __shfl_xor(sum, 32);
    const float invs = 1.0f / sum;
    const int i = ti*32 + l31;
    const int sw = (i & 7) << 4;
#pragma unroll
    for (int mt = 0; mt < 2; mt++)
#pragma unroll
      for (int g = 0; g < 4; g++){
        ushort4 pk;
        pk.x = f2bf(s[mt][ti][4*g + 0] * invs);
        pk.y = f2bf(s[mt][ti][4*g + 1] * invs);
        pk.z = f2bf(s[mt][ti][4*g + 2] * invs);
        pk.w = f2bf(s[mt][ti][4*g + 3] * invs);
        const int jbyte = mt*64 + g*16 + hi*8;
        *(ushort4*)(pbase + ((i*128 + jbyte) ^ sw)) = pk;
      }
  }
  __syncthreads();

  f32x4 o[4] = {};
#pragma unroll
  for (int nt = 0; nt < 4; nt++){
    const int n = nt*16 + l15;
    const int swr = (n & 7) << 4;
#pragma unroll
    for (int kc = 0; kc < 2; kc++){
      bf16x8 pb = *(const bf16x8*)(pbase + ((n*128 + kc*64 + qg*16) ^ swr));
      o[nt] = __builtin_amdgcn_mfma_f32_16x16x32_bf16(vf[kc], pb, o[nt], 0, 0, 0);
    }
  }

  const size_t base = (size_t)token * D_MODEL;
#pragma unroll
  for (int nt = 0; nt < 4; nt++){
    const int i = nt*16 + l15;
    const float4 iv = *(const float4*)(inp + base + i*16 + qg*4);
    float4 ov;
    ov.x = iv.x + o[nt][0];
    ov.y = iv.y + o[nt][1];
    ov.z = iv.z + o[nt][2];
    ov.w = iv.w + o[nt][3];
    *(float4*)(out + base + i*16 + qg*4) = ov;
  }
}

extern "C" void kernel_launch(void* const* d_in, const int* in_sizes, int n_in,
                              void* d_out, int out_size, void* d_ws, size_t ws_size,
                              hipStream_t stream) {
  const float* inp   = (const float*)d_in[0];
  const float* Wq    = (const float*)d_in[1];
  const float* bq    = (const float*)d_in[2];
  const float* Wk    = (const float*)d_in[3];
  const float* bk    = (const float*)d_in[4];
  const float* Wv    = (const float*)d_in[5];
  const float* bv    = (const float*)d_in[6];
  const float* gamma = (const float*)d_in[7];
  const float* beta  = (const float*)d_in[8];
  float* out = (float*)d_out;

  char* ws = (char*)d_ws;
  unsigned short* Xln  = (unsigned short*)ws;                 // 8192*1024*2  = 16,777,216 B
  unsigned short* Wt   = (unsigned short*)(ws + 16777216);    // 3072*1024*2  =  6,291,456 B
  float*          bc   = (float*)(ws + 23068672);             // 3072*4       =     12,288 B
  unsigned short* QKV  = (unsigned short*)(ws + 23080960);    // 8192*3072*2  = 50,331,648 B

  ln_kernel<<<8192, 256, 0, stream>>>(inp, gamma, beta, Xln);
  wtrans_kernel<<<dim3(32, 32, 3), 256, 0, stream>>>(Wq, Wk, Wv, bq, bk, bv, Wt, bc);
  gemm128x256_kernel<<<768, 512, 0, stream>>>(Xln, Wt, bc, QKV);
  attn_kernel<<<2048, 256, 0, stream>>>(QKV, inp, out);
}

// Round 16
// 94.126 us; speedup vs baseline: 1.0441x; 1.0441x over previous
//
#include <hip/hip_runtime.h>
#include <hip/hip_bf16.h>

#define D_MODEL 1024
#define NQKV 3072

typedef __attribute__((ext_vector_type(8))) short bf16x8;
typedef __attribute__((ext_vector_type(4))) float f32x4;
typedef __attribute__((ext_vector_type(16))) float f32x16;
typedef __attribute__((ext_vector_type(8))) unsigned short u16x8;

static __device__ __forceinline__ unsigned short f2bf(float f){
  unsigned int x = __float_as_uint(f);
  x += 0x7fff + ((x >> 16) & 1);   // RNE
  return (unsigned short)(x >> 16);
}
static __device__ __forceinline__ float bf2f(unsigned short u){
  return __uint_as_float(((unsigned int)u) << 16);
}

// ====== fused prologue: blocks 0..8191 = LayerNorm rows; 8192..11263 = W transpose ======
// LN and wtrans are independent — fusing overlaps wtrans (~3us) under LN (~8us)
// and removes one launch gap.
__global__ __launch_bounds__(256) void fused_pre_kernel(const float* __restrict__ inp,
    const float* __restrict__ gamma, const float* __restrict__ beta,
    const float* __restrict__ Wq, const float* __restrict__ Wk,
    const float* __restrict__ Wv, const float* __restrict__ bq,
    const float* __restrict__ bk, const float* __restrict__ bv,
    unsigned short* __restrict__ X, unsigned short* __restrict__ Wt,
    float* __restrict__ bc){
  if (blockIdx.x < 8192){
    // ---------------- LayerNorm -> bf16 ----------------
    const int row = blockIdx.x;
    const int t = threadIdx.x;
    const float4* ip = (const float4*)(inp + (size_t)row * D_MODEL);
    float4 v = ip[t];
    float s1 = v.x + v.y + v.z + v.w;
    float s2 = v.x*v.x + v.y*v.y + v.z*v.z + v.w*v.w;
#pragma unroll
    for (int off = 32; off >= 1; off >>= 1){
      s1 += __shfl_down(s1, off);
      s2 += __shfl_down(s2, off);
    }
    __shared__ float red[8];
    const int wave = t >> 6, lane = t & 63;
    if (lane == 0){ red[wave] = s1; red[4 + wave] = s2; }
    __syncthreads();
    s1 = red[0] + red[1] + red[2] + red[3];
    s2 = red[4] + red[5] + red[6] + red[7];
    const float mu   = s1 * (1.0f / D_MODEL);
    const float var  = s2 * (1.0f / D_MODEL) - mu * mu;
    const float rstd = rsqrtf(var + 1e-5f);
    float4 g = ((const float4*)gamma)[t];
    float4 b = ((const float4*)beta)[t];
    ushort4 o;
    o.x = f2bf((v.x - mu) * rstd * g.x + b.x);
    o.y = f2bf((v.y - mu) * rstd * g.y + b.y);
    o.z = f2bf((v.z - mu) * rstd * g.z + b.z);
    o.w = f2bf((v.w - mu) * rstd * g.w + b.w);
    ((ushort4*)(X + (size_t)row * D_MODEL))[t] = o;
  } else {
    // --- W transpose + fp32->bf16 (Wt[n][k] = W[k][n]) + fused bias concat ---
    __shared__ float tile[32][33];
    const int idx = blockIdx.x - 8192;             // 0..3071
    const int kx = idx & 31, ny = (idx >> 5) & 31, z = idx >> 10;
    const float* W = (z == 0) ? Wq : ((z == 1) ? Wk : Wv);
    const int k0 = kx * 32, n0 = ny * 32;
    const int r = threadIdx.x >> 5, c = threadIdx.x & 31;
    if (kx == 0 && r == 0){
      const float* bsrc = (z == 0) ? bq : ((z == 1) ? bk : bv);
      bc[z * 1024 + n0 + c] = bsrc[n0 + c];
    }
#pragma unroll
    for (int i = 0; i < 4; i++)
      tile[r + i*8][c] = W[(size_t)(k0 + r + i*8) * D_MODEL + n0 + c];
    __syncthreads();
    unsigned short* dst = Wt + (size_t)(z * D_MODEL + n0) * D_MODEL + k0;
#pragma unroll
    for (int i = 0; i < 4; i++){
      int rr = r + i*8;
      dst[(size_t)rr * D_MODEL + c] = f2bf(tile[c][rr]);
    }
  }
}

// ====== 128x256 GEMM, BK=64, 3-buffer T3-order pipeline + 2D XCD chunks (R14) ======
// QKV[8192][3072] = Xln @ Wt^T + b.  A row-major, Bt [N][K] K-major.
// Proven best (R14, 63.4us / 812 TF): STAGE(t+2); BODY(t); vmcnt(6); s_barrier;
// 2D XCD-chunked mapping keeps each XCD's A-chunk (2MB) L2-resident
// (FETCH 104->49MB, the verified mechanism). LDS XOR-swizzle byte ^= ((row&7)<<4),
// pre-swizzled global source; 0 bank conflicts.

#define GLL(src, dst) __builtin_amdgcn_global_load_lds( \
    (const __attribute__((address_space(1))) void*)(src), \
    (__attribute__((address_space(3))) void*)(dst), 16, 0, 0)

#define STAGE(tsrc, bi) do { \
  const char* _sa = Ag + (size_t)r0*2048 + (size_t)(tsrc)*128 + co; \
  char* _da = ldsS + (size_t)(bi)*49152 + tid*16; \
  GLL(_sa, _da); GLL(_sa + 131072, _da + 8192); \
  const char* _sb = Bg + (size_t)r0*2048 + (size_t)(tsrc)*128 + co; \
  char* _db = ldsS + (size_t)(bi)*49152 + 16384 + tid*16; \
  GLL(_sb, _db); GLL(_sb + 131072, _db + 8192); \
  GLL(_sb + 262144, _db + 16384); GLL(_sb + 393216, _db + 24576); \
} while(0)

#define BODY(bi) do { \
  const char* Ab = ldsS + (size_t)(bi)*49152 + (wr*64 + lr)*128; \
  const char* Bb = ldsS + (size_t)(bi)*49152 + 16384 + (wc*64 + lr)*128; \
  bf16x8 Ar[4][2], Br[4][2]; \
  _Pragma("unroll") \
  for (int m = 0; m < 4; m++){ \
    Ar[m][0] = *(const bf16x8*)(Ab + m*2048 + colb0); \
    Ar[m][1] = *(const bf16x8*)(Ab + m*2048 + colb1); \
  } \
  _Pragma("unroll") \
  for (int n = 0; n < 4; n++){ \
    Br[n][0] = *(const bf16x8*)(Bb + n*2048 + colb0); \
    Br[n][1] = *(const bf16x8*)(Bb + n*2048 + colb1); \
  } \
  _Pragma("unroll") \
  for (int m = 0; m < 4; m++) \
    _Pragma("unroll") \
    for (int n = 0; n < 4; n++){ \
      acc[m][n] = __builtin_amdgcn_mfma_f32_16x16x32_bf16(Ar[m][0], Br[n][0], acc[m][n], 0, 0, 0); \
      acc[m][n] = __builtin_amdgcn_mfma_f32_16x16x32_bf16(Ar[m][1], Br[n][1], acc[m][n], 0, 0, 0); \
    } \
} while(0)

#define BARRIER __builtin_amdgcn_s_barrier()
#define SCHEDB  __builtin_amdgcn_sched_barrier(0)
#define VMCNT6  asm volatile("s_waitcnt vmcnt(6)" ::: "memory")
#define VMCNT0  asm volatile("s_waitcnt vmcnt(0)" ::: "memory")

__global__ __launch_bounds__(512, 2) void gemm128x256_kernel(const unsigned short* __restrict__ A,
    const unsigned short* __restrict__ Bt, const float* __restrict__ bias,
    unsigned short* __restrict__ C){
  __shared__ __align__(16) char ldsS[3 * 49152];   // 144 KiB
  const int tid = threadIdx.x;
  const int wave = tid >> 6, lane = tid & 63;
  const int wr = wave >> 2, wc = wave & 3;         // 2M x 4N wave grid
  const int lr = lane & 15;
  const int colb0 = ((lane >> 4) * 16) ^ ((lane & 7) << 4);
  const int colb1 = (64 + (lane >> 4) * 16) ^ ((lane & 7) << 4);

  // 2D XCD-chunked mapping: XCD x owns M-tiles [x*8, x*8+8) x all 12 N-tiles.
  const int b = blockIdx.x;
  const int xcd = b & 7;
  const int i = b >> 3;                            // 0..95 within XCD
  const int mi = i & 7, ni = i >> 3;               // 8 M x 12 N, M fastest
  const int m0 = (xcd * 8 + mi) * 128;
  const int n0 = ni * 256;

  const int r0 = tid >> 3;
  const size_t co = (size_t)(((tid & 7) * 16) ^ ((r0 & 7) << 4));
  const char* Ag = (const char*)(A + (size_t)m0 * 1024);
  const char* Bg = (const char*)(Bt + (size_t)n0 * 1024);

  f32x4 acc[4][4] = {};

  // prologue: stage tiles 0,1 into bufs 0,1; require tile 0 landed (tile 1 may fly)
  STAGE(0, 0);
  STAGE(1, 1);
  VMCNT6; BARRIER; SCHEDB;

  for (int t = 0; t < 16; ++t){
    if (t <= 13) STAGE(t + 2, (t + 2) % 3);   // issue FIRST — pipe stays fed through the wait
    BODY(t % 3);
    if (t <= 13)      { SCHEDB; VMCNT6; BARRIER; SCHEDB; }  // tile t+1 landed; t+2 in flight
    else if (t == 14) { SCHEDB; VMCNT0; BARRIER; SCHEDB; }  // tile 15 fully landed
    // t == 15: no wait/barrier — epilogue is LDS-free
  }

  // epilogue: bias + bf16 store (per-wave 64x64)
  const int gm = m0 + wr*64;
  const int gn = n0 + wc*64;
  const int rr0 = (lane >> 4) * 4;
#pragma unroll
  for (int nf = 0; nf < 4; nf++){
    const int gcol = gn + nf*16 + lr;
    const float bb = bias[gcol];
#pragma unroll
    for (int mf = 0; mf < 4; mf++){
      const int grow = gm + mf*16 + rr0;
#pragma unroll
      for (int r = 0; r < 4; r++)
        C[(size_t)(grow + r) * NQKV + gcol] = f2bf(acc[mf][nf][r] + bb);
    }
  }
}

// ---------------- per-token attention + residual (MFMA, swapped-QK^T) ----------------
__global__ __launch_bounds__(256) void attn_kernel(const unsigned short* __restrict__ qkv,
    const float* __restrict__ inp, float* __restrict__ out){
  __shared__ unsigned short P[4][64 * 64];
  const int wave = threadIdx.x >> 6, lane = threadIdx.x & 63;
  const int token = blockIdx.x * 4 + wave;
  const unsigned short* row = qkv + (size_t)token * NQKV;
  const int l31 = lane & 31, hi = lane >> 5;
  const int l15 = lane & 15, qg = lane >> 4;
  char* pbase = (char*)&P[wave][0];

  bf16x8 kf[2], qf[2];
#pragma unroll
  for (int mt = 0; mt < 2; mt++)
    kf[mt] = *(const bf16x8*)(row + 1024 + (mt*32 + l31)*16 + hi*8);
#pragma unroll
  for (int nt = 0; nt < 2; nt++)
    qf[nt] = *(const bf16x8*)(row + (nt*32 + l31)*16 + hi*8);

  bf16x8 vf[2];
#pragma unroll
  for (int kc = 0; kc < 2; kc++)
#pragma unroll
    for (int e = 0; e < 8; e++)
      vf[kc][e] = (short)row[2048 + (kc*32 + qg*8 + e)*16 + l15];

  f32x16 s[2][2] = {};
#pragma unroll
  for (int mt = 0; mt < 2; mt++)
#pragma unroll
    for (int nt = 0; nt < 2; nt++)
      s[mt][nt] = __builtin_amdgcn_mfma_f32_32x32x16_bf16(kf[mt], qf[nt], s[mt][nt], 0, 0, 0);

#pragma unroll
  for (int ti = 0; ti < 2; ti++){
    float m = s[0][ti][0];
#pragma unroll
    for (int mt = 0; mt < 2; mt++)
#pragma unroll
      for (int r = 0; r < 16; r++) m = fmaxf(m, s[mt][ti][r]);
    m = fmaxf(m, __shfl_xor(m, 32));
    float sum = 0.0f;
#pragma unroll
    for (int mt = 0; mt < 2; mt++)
#pragma unroll
      for (int r = 0; r < 16; r++){
        float p = exp2f((s[mt][ti][r] - m) * 0.1803368801f); // 0.125 * log2(e)
        s[mt][ti][r] = p;
        sum += p;
      }
    sum += __shfl_xor(sum, 32);
    const float invs = 1.0f / sum;
    const int i = ti*32 + l31;
    const int sw = (i & 7) << 4;
#pragma unroll
    for (int mt = 0; mt < 2; mt++)
#pragma unroll
      for (int g = 0; g < 4; g++){
        ushort4 pk;
        pk.x = f2bf(s[mt][ti][4*g + 0] * invs);
        pk.y = f2bf(s[mt][ti][4*g + 1] * invs);
        pk.z = f2bf(s[mt][ti][4*g + 2] * invs);
        pk.w = f2bf(s[mt][ti][4*g + 3] * invs);
        const int jbyte = mt*64 + g*16 + hi*8;
        *(ushort4*)(pbase + ((i*128 + jbyte) ^ sw)) = pk;
      }
  }
  __syncthreads();

  f32x4 o[4] = {};
#pragma unroll
  for (int nt = 0; nt < 4; nt++){
    const int n = nt*16 + l15;
    const int swr = (n & 7) << 4;
#pragma unroll
    for (int kc = 0; kc < 2; kc++){
      bf16x8 pb = *(const bf16x8*)(pbase + ((n*128 + kc*64 + qg*16) ^ swr));
      o[nt] = __builtin_amdgcn_mfma_f32_16x16x32_bf16(vf[kc], pb, o[nt], 0, 0, 0);
    }
  }

  const size_t base = (size_t)token * D_MODEL;
#pragma unroll
  for (int nt = 0; nt < 4; nt++){
    const int i = nt*16 + l15;
    const float4 iv = *(const float4*)(inp + base + i*16 + qg*4);
    float4 ov;
    ov.x = iv.x + o[nt][0];
    ov.y = iv.y + o[nt][1];
    ov.z = iv.z + o[nt][2];
    ov.w = iv.w + o[nt][3];
    *(float4*)(out + base + i*16 + qg*4) = ov;
  }
}

extern "C" void kernel_launch(void* const* d_in, const int* in_sizes, int n_in,
                              void* d_out, int out_size, void* d_ws, size_t ws_size,
                              hipStream_t stream) {
  const float* inp   = (const float*)d_in[0];
  const float* Wq    = (const float*)d_in[1];
  const float* bq    = (const float*)d_in[2];
  const float* Wk    = (const float*)d_in[3];
  const float* bk    = (const float*)d_in[4];
  const float* Wv    = (const float*)d_in[5];
  const float* bv    = (const float*)d_in[6];
  const float* gamma = (const float*)d_in[7];
  const float* beta  = (const float*)d_in[8];
  float* out = (float*)d_out;

  char* ws = (char*)d_ws;
  unsigned short* Xln  = (unsigned short*)ws;                 // 8192*1024*2  = 16,777,216 B
  unsigned short* Wt   = (unsigned short*)(ws + 16777216);    // 3072*1024*2  =  6,291,456 B
  float*          bc   = (float*)(ws + 23068672);             // 3072*4       =     12,288 B
  unsigned short* QKV  = (unsigned short*)(ws + 23080960);    // 8192*3072*2  = 50,331,648 B

  fused_pre_kernel<<<11264, 256, 0, stream>>>(inp, gamma, beta, Wq, Wk, Wv,
                                              bq, bk, bv, Xln, Wt, bc);
  gemm128x256_kernel<<<768, 512, 0, stream>>>(Xln, Wt, bc, QKV);
  attn_kernel<<<2048, 256, 0, stream>>>(QKV, inp, out);
}

// Round 17
// 92.074 us; speedup vs baseline: 1.0674x; 1.0223x over previous
//
#include <hip/hip_runtime.h>
#include <hip/hip_bf16.h>

#define D_MODEL 1024
#define NQKV 3072

typedef __attribute__((ext_vector_type(8))) short bf16x8;
typedef __attribute__((ext_vector_type(4))) float f32x4;
typedef __attribute__((ext_vector_type(16))) float f32x16;
typedef __attribute__((ext_vector_type(8))) unsigned short u16x8;

static __device__ __forceinline__ unsigned short f2bf(float f){
  unsigned int x = __float_as_uint(f);
  x += 0x7fff + ((x >> 16) & 1);   // RNE
  return (unsigned short)(x >> 16);
}
static __device__ __forceinline__ float bf2f(unsigned short u){
  return __uint_as_float(((unsigned int)u) << 16);
}

// ====== fused prologue: blocks 0..8191 = LayerNorm rows; 8192..11263 = W transpose ======
__global__ __launch_bounds__(256) void fused_pre_kernel(const float* __restrict__ inp,
    const float* __restrict__ gamma, const float* __restrict__ beta,
    const float* __restrict__ Wq, const float* __restrict__ Wk,
    const float* __restrict__ Wv, const float* __restrict__ bq,
    const float* __restrict__ bk, const float* __restrict__ bv,
    unsigned short* __restrict__ X, unsigned short* __restrict__ Wt,
    float* __restrict__ bc){
  if (blockIdx.x < 8192){
    const int row = blockIdx.x;
    const int t = threadIdx.x;
    const float4* ip = (const float4*)(inp + (size_t)row * D_MODEL);
    float4 v = ip[t];
    float s1 = v.x + v.y + v.z + v.w;
    float s2 = v.x*v.x + v.y*v.y + v.z*v.z + v.w*v.w;
#pragma unroll
    for (int off = 32; off >= 1; off >>= 1){
      s1 += __shfl_down(s1, off);
      s2 += __shfl_down(s2, off);
    }
    __shared__ float red[8];
    const int wave = t >> 6, lane = t & 63;
    if (lane == 0){ red[wave] = s1; red[4 + wave] = s2; }
    __syncthreads();
    s1 = red[0] + red[1] + red[2] + red[3];
    s2 = red[4] + red[5] + red[6] + red[7];
    const float mu   = s1 * (1.0f / D_MODEL);
    const float var  = s2 * (1.0f / D_MODEL) - mu * mu;
    const float rstd = rsqrtf(var + 1e-5f);
    float4 g = ((const float4*)gamma)[t];
    float4 b = ((const float4*)beta)[t];
    ushort4 o;
    o.x = f2bf((v.x - mu) * rstd * g.x + b.x);
    o.y = f2bf((v.y - mu) * rstd * g.y + b.y);
    o.z = f2bf((v.z - mu) * rstd * g.z + b.z);
    o.w = f2bf((v.w - mu) * rstd * g.w + b.w);
    ((ushort4*)(X + (size_t)row * D_MODEL))[t] = o;
  } else {
    __shared__ float tile[32][33];
    const int idx = blockIdx.x - 8192;             // 0..3071
    const int kx = idx & 31, ny = (idx >> 5) & 31, z = idx >> 10;
    const float* W = (z == 0) ? Wq : ((z == 1) ? Wk : Wv);
    const int k0 = kx * 32, n0 = ny * 32;
    const int r = threadIdx.x >> 5, c = threadIdx.x & 31;
    if (kx == 0 && r == 0){
      const float* bsrc = (z == 0) ? bq : ((z == 1) ? bk : bv);
      bc[z * 1024 + n0 + c] = bsrc[n0 + c];
    }
#pragma unroll
    for (int i = 0; i < 4; i++)
      tile[r + i*8][c] = W[(size_t)(k0 + r + i*8) * D_MODEL + n0 + c];
    __syncthreads();
    unsigned short* dst = Wt + (size_t)(z * D_MODEL + n0) * D_MODEL + k0;
#pragma unroll
    for (int i = 0; i < 4; i++){
      int rr = r + i*8;
      dst[(size_t)rr * D_MODEL + c] = f2bf(tile[c][rr]);
    }
  }
}

// ====== persistent 128x256 GEMM: 256 blocks (1/CU), 3 N-tiles per block ======
// QKV[8192][3072] = Xln @ Wt^T + b.  A row-major, Bt [N][K] K-major.
// R17 (vs R14/R16, single variable): grid 768 -> 256 persistent. With the 2D
// XCD mapping, blocks j, j+32, j+64 share the SAME mi (32 == 0 mod 8), so one
// block processes 3 N-tiles of ONE A panel: a unified 48-step K-pipeline with
// cross-tile staging (tile p+1's K-tiles 0,1 staged at p's t=14,15) — the
// pipeline never drains at tile boundaries, and each tile's epilogue issues
// after the (p,15) barrier so its stores retire under p+1's BODY. Removes the
// 3-round fills/drains/exposed-epilogues of the 768-grid. Wait schedule is the
// continuous extension of R14: buf=(p+t)%3; vmcnt(6) everywhere except global
// step 46 -> vmcnt(0), 47 -> none. Race audit unchanged (3 buffers; stage
// target's reads completed >= 2 barriers earlier; vmcnt(6) at iter end
// guarantees next tile landed). Epilogue stores inflate vmcnt afterwards ->
// vmcnt(6) over-waits on them once, a full BODY later (retired by then).
// LDS XOR-swizzle byte ^= ((row&7)<<4); pre-swizzled global source.

#define GLL(src, dst) __builtin_amdgcn_global_load_lds( \
    (const __attribute__((address_space(1))) void*)(src), \
    (__attribute__((address_space(3))) void*)(dst), 16, 0, 0)

#define STAGE2(AG, BG, tsrc, bi) do { \
  const char* _sa = (AG) + (size_t)r0*2048 + (size_t)(tsrc)*128 + co; \
  char* _da = ldsS + (size_t)(bi)*49152 + tid*16; \
  GLL(_sa, _da); GLL(_sa + 131072, _da + 8192); \
  const char* _sb = (BG) + (size_t)r0*2048 + (size_t)(tsrc)*128 + co; \
  char* _db = ldsS + (size_t)(bi)*49152 + 16384 + tid*16; \
  GLL(_sb, _db); GLL(_sb + 131072, _db + 8192); \
  GLL(_sb + 262144, _db + 16384); GLL(_sb + 393216, _db + 24576); \
} while(0)

#define BODY(bi) do { \
  const char* Ab = ldsS + (size_t)(bi)*49152 + (wr*64 + lr)*128; \
  const char* Bb = ldsS + (size_t)(bi)*49152 + 16384 + (wc*64 + lr)*128; \
  bf16x8 Ar[4][2], Br[4][2]; \
  _Pragma("unroll") \
  for (int m = 0; m < 4; m++){ \
    Ar[m][0] = *(const bf16x8*)(Ab + m*2048 + colb0); \
    Ar[m][1] = *(const bf16x8*)(Ab + m*2048 + colb1); \
  } \
  _Pragma("unroll") \
  for (int n = 0; n < 4; n++){ \
    Br[n][0] = *(const bf16x8*)(Bb + n*2048 + colb0); \
    Br[n][1] = *(const bf16x8*)(Bb + n*2048 + colb1); \
  } \
  _Pragma("unroll") \
  for (int m = 0; m < 4; m++) \
    _Pragma("unroll") \
    for (int n = 0; n < 4; n++){ \
      acc[m][n] = __builtin_amdgcn_mfma_f32_16x16x32_bf16(Ar[m][0], Br[n][0], acc[m][n], 0, 0, 0); \
      acc[m][n] = __builtin_amdgcn_mfma_f32_16x16x32_bf16(Ar[m][1], Br[n][1], acc[m][n], 0, 0, 0); \
    } \
} while(0)

#define BARRIER __builtin_amdgcn_s_barrier()
#define SCHEDB  __builtin_amdgcn_sched_barrier(0)
#define VMCNT6  asm volatile("s_waitcnt vmcnt(6)" ::: "memory")
#define VMCNT0  asm volatile("s_waitcnt vmcnt(0)" ::: "memory")

__global__ __launch_bounds__(512, 2) void gemm_pers_kernel(const unsigned short* __restrict__ A,
    const unsigned short* __restrict__ Bt, const float* __restrict__ bias,
    unsigned short* __restrict__ C){
  __shared__ __align__(16) char ldsS[3 * 49152];   // 144 KiB
  const int tid = threadIdx.x;
  const int wave = tid >> 6, lane = tid & 63;
  const int wr = wave >> 2, wc = wave & 3;         // 2M x 4N wave grid
  const int lr = lane & 15;
  const int colb0 = ((lane >> 4) * 16) ^ ((lane & 7) << 4);
  const int colb1 = (64 + (lane >> 4) * 16) ^ ((lane & 7) << 4);

  // persistent 2D XCD mapping: block b -> xcd = b&7, j = b>>3 (0..31).
  // Tiles p=0,1,2: mi = j&7 (same A panel all p), ni = (j>>3) + 4p.
  const int b = blockIdx.x;
  const int xcd = b & 7;
  const int j = b >> 3;
  const int mi = j & 7;
  const int ni0 = j >> 3;                          // 0..3
  const int m0 = (xcd * 8 + mi) * 128;
  const int n00 = ni0 * 256;

  const int r0 = tid >> 3;
  const size_t co = (size_t)(((tid & 7) * 16) ^ ((r0 & 7) << 4));
  const char* Ag  = (const char*)(A + (size_t)m0 * 1024);
  const char* Bg0 = (const char*)(Bt + (size_t)n00 * 1024);

  f32x4 acc[4][4] = {};

  // prologue: stage (p=0, t=0,1) into bufs 0,1; require t=0 landed
  STAGE2(Ag, Bg0, 0, 0);
  STAGE2(Ag, Bg0, 1, 1);
  VMCNT6; BARRIER; SCHEDB;

#pragma unroll
  for (int p = 0; p < 3; ++p){
    const char* Bp  = Bg0 + (size_t)p * 2097152;        // +p*1024 cols * 1024 K * 2B
    const char* Bp1 = Bg0 + (size_t)(p + 1) * 2097152;
    for (int t = 0; t < 16; ++t){
      // stage global step s+2 (cross-tile at t=14,15)
      if (t <= 13)     STAGE2(Ag, Bp,  t + 2,  (p + t + 2) % 3);
      else if (p < 2)  STAGE2(Ag, Bp1, t - 14, (p + t + 2) % 3);
      BODY((p + t) % 3);
      if (p < 2){
        SCHEDB; VMCNT6; BARRIER; SCHEDB;                // next tile's step landed
      } else {
        if (t <= 13)      { SCHEDB; VMCNT6; BARRIER; SCHEDB; }
        else if (t == 14) { SCHEDB; VMCNT0; BARRIER; SCHEDB; }
        // t == 15: no wait — epilogue is LDS-free
      }
    }
    // epilogue for tile p (after barrier; stores retire under next tile's BODY)
    {
      const int gm = m0 + wr * 64;
      const int gn = n00 + p * 1024 + wc * 64;
      const int rr0 = (lane >> 4) * 4;
#pragma unroll
      for (int nf = 0; nf < 4; nf++){
        const int gcol = gn + nf*16 + lr;
        const float bb = bias[gcol];
#pragma unroll
        for (int mf = 0; mf < 4; mf++){
          const int grow = gm + mf*16 + rr0;
#pragma unroll
          for (int r = 0; r < 4; r++)
            C[(size_t)(grow + r) * NQKV + gcol] = f2bf(acc[mf][nf][r] + bb);
        }
      }
    }
    if (p < 2){
#pragma unroll
      for (int m = 0; m < 4; m++)
#pragma unroll
        for (int n = 0; n < 4; n++)
          acc[m][n] = (f32x4){0.0f, 0.0f, 0.0f, 0.0f};
    }
  }
}

// ---------------- per-token attention + residual (MFMA, swapped-QK^T) ----------------
__global__ __launch_bounds__(256) void attn_kernel(const unsigned short* __restrict__ qkv,
    const float* __restrict__ inp, float* __restrict__ out){
  __shared__ unsigned short P[4][64 * 64];
  const int wave = threadIdx.x >> 6, lane = threadIdx.x & 63;
  const int token = blockIdx.x * 4 + wave;
  const unsigned short* row = qkv + (size_t)token * NQKV;
  const int l31 = lane & 31, hi = lane >> 5;
  const int l15 = lane & 15, qg = lane >> 4;
  char* pbase = (char*)&P[wave][0];

  bf16x8 kf[2], qf[2];
#pragma unroll
  for (int mt = 0; mt < 2; mt++)
    kf[mt] = *(const bf16x8*)(row + 1024 + (mt*32 + l31)*16 + hi*8);
#pragma unroll
  for (int nt = 0; nt < 2; nt++)
    qf[nt] = *(const bf16x8*)(row + (nt*32 + l31)*16 + hi*8);

  bf16x8 vf[2];
#pragma unroll
  for (int kc = 0; kc < 2; kc++)
#pragma unroll
    for (int e = 0; e < 8; e++)
      vf[kc][e] = (short)row[2048 + (kc*32 + qg*8 + e)*16 + l15];

  f32x16 s[2][2] = {};
#pragma unroll
  for (int mt = 0; mt < 2; mt++)
#pragma unroll
    for (int nt = 0; nt < 2; nt++)
      s[mt][nt] = __builtin_amdgcn_mfma_f32_32x32x16_bf16(kf[mt], qf[nt], s[mt][nt], 0, 0, 0);

#pragma unroll
  for (int ti = 0; ti < 2; ti++){
    float m = s[0][ti][0];
#pragma unroll
    for (int mt = 0; mt < 2; mt++)
#pragma unroll
      for (int r = 0; r < 16; r++) m = fmaxf(m, s[mt][ti][r]);
    m = fmaxf(m, __shfl_xor(m, 32));
    float sum = 0.0f;
#pragma unroll
    for (int mt = 0; mt < 2; mt++)
#pragma unroll
      for (int r = 0; r < 16; r++){
        float p = exp2f((s[mt][ti][r] - m) * 0.1803368801f); // 0.125 * log2(e)
        s[mt][ti][r] = p;
        sum += p;
      }
    sum += __shfl_xor(sum, 32);
    const float invs = 1.0f / sum;
    const int i = ti*32 + l31;
    const int sw = (i & 7) << 4;
#pragma unroll
    for (int mt = 0; mt < 2; mt++)
#pragma unroll
      for (int g = 0; g < 4; g++){
        ushort4 pk;
        pk.x = f2bf(s[mt][ti][4*g + 0] * invs);
        pk.y = f2bf(s[mt][ti][4*g + 1] * invs);
        pk.z = f2bf(s[mt][ti][4*g + 2] * invs);
        pk.w = f2bf(s[mt][ti][4*g + 3] * invs);
        const int jbyte = mt*64 + g*16 + hi*8;
        *(ushort4*)(pbase + ((i*128 + jbyte) ^ sw)) = pk;
      }
  }
  __syncthreads();

  f32x4 o[4] = {};
#pragma unroll
  for (int nt = 0; nt < 4; nt++){
    const int n = nt*16 + l15;
    const int swr = (n & 7) << 4;
#pragma unroll
    for (int kc = 0; kc < 2; kc++){
      bf16x8 pb = *(const bf16x8*)(pbase + ((n*128 + kc*64 + qg*16) ^ swr));
      o[nt] = __builtin_amdgcn_mfma_f32_16x16x32_bf16(vf[kc], pb, o[nt], 0, 0, 0);
    }
  }

  const size_t base = (size_t)token * D_MODEL;
#pragma unroll
  for (int nt = 0; nt < 4; nt++){
    const int i = nt*16 + l15;
    const float4 iv = *(const float4*)(inp + base + i*16 + qg*4);
    float4 ov;
    ov.x = iv.x + o[nt][0];
    ov.y = iv.y + o[nt][1];
    ov.z = iv.z + o[nt][2];
    ov.w = iv.w + o[nt][3];
    *(float4*)(out + base + i*16 + qg*4) = ov;
  }
}

extern "C" void kernel_launch(void* const* d_in, const int* in_sizes, int n_in,
                              void* d_out, int out_size, void* d_ws, size_t ws_size,
                              hipStream_t stream) {
  const float* inp   = (const float*)d_in[0];
  const float* Wq    = (const float*)d_in[1];
  const float* bq    = (const float*)d_in[2];
  const float* Wk    = (const float*)d_in[3];
  const float* bk    = (const float*)d_in[4];
  const float* Wv    = (const float*)d_in[5];
  const float* bv    = (const float*)d_in[6];
  const float* gamma = (const float*)d_in[7];
  const float* beta  = (const float*)d_in[8];
  float* out = (float*)d_out;

  char* ws = (char*)d_ws;
  unsigned short* Xln  = (unsigned short*)ws;                 // 8192*1024*2  = 16,777,216 B
  unsigned short* Wt   = (unsigned short*)(ws + 16777216);    // 3072*1024*2  =  6,291,456 B
  float*          bc   = (float*)(ws + 23068672);             // 3072*4       =     12,288 B
  unsigned short* QKV  = (unsigned short*)(ws + 23080960);    // 8192*3072*2  = 50,331,648 B

  fused_pre_kernel<<<11264, 256, 0, stream>>>(inp, gamma, beta, Wq, Wk, Wv,
                                              bq, bk, bv, Xln, Wt, bc);
  gemm_pers_kernel<<<256, 512, 0, stream>>>(Xln, Wt, bc, QKV);
  attn_kernel<<<2048, 256, 0, stream>>>(QKV, inp, out);
}